// Round 2
// 860.148 us; speedup vs baseline: 1.0083x; 1.0083x over previous
//
#include <hip/hip_runtime.h>
#include <math.h>

// ---------------------------------------------------------------------------
// ContrastiveEnergyLearning: fused bf16-MFMA MLP energy + contrastive loss
// R3 (resubmit — R1 bench was a GPU-acquisition timeout, no data):
// occupancy attack. fused_k latency-bound at 3 blocks/CU (51.2KB LDS,
// ~150 VGPR, 7 barrier-lockstep phases). New: M=32 tile (acc 64->32 VGPR),
// LDS 51.2KB -> 19.9KB (h2 overlays h1, h3 eliminated), launch_bounds(256,6)
// -> 6 waves/SIMD. Biases/apre folded into MFMA C-in. Layer4 in-register via
// shfl_xor reduce. cvt_pk-paired bf16 converts in all epilogues.
// ---------------------------------------------------------------------------

#define NROWS 32768
#define NC 17
#define NPAIRS (NROWS * NC)   // 557056 = 32 * 17408
#define INV_T (1.0f / 0.07f)

using bf16x8 = __attribute__((ext_vector_type(8))) short;
using f32x4  = __attribute__((ext_vector_type(4))) float;

// packed weight layout (bf16 element offsets in ws)
#define PK_W1A 0         // 128 tiles * 512
#define PK_W1Y 65536     // 128 tiles * 512
#define PK_W2  131072    // 64 tiles * 512
#define PK_W3  163840    // 16 tiles * 512
#define APRE_OFF_BYTES 344064
#define EN_OFF_BYTES   (344064 + (size_t)NROWS * 256 * 4)

__device__ inline unsigned short f2b(float f) {
  union { float f; unsigned u; } v; v.f = f;
  return (unsigned short)((v.u + 0x7FFFu + ((v.u >> 16) & 1u)) >> 16);
}
__device__ inline unsigned f2b2(float a, float b) {   // pack two bf16 (RNE) into u32
#if __has_builtin(__builtin_amdgcn_cvt_pk_bf16_f32)
  typedef __attribute__((ext_vector_type(2))) short s2;
  union { s2 s; unsigned u; } v; v.s = __builtin_amdgcn_cvt_pk_bf16_f32(a, b);
  return v.u;
#else
  return (unsigned)f2b(a) | ((unsigned)f2b(b) << 16);
#endif
}
__device__ inline float b2f(unsigned short b) {
  union { unsigned u; float f; } v; v.u = ((unsigned)b) << 16; return v.f;
}
// tanh-form GELU: x * sigmoid(1.5957691x + 0.0713584x^3). ~8 VALU ops.
// max |delta| vs exact-erf gelu ~3e-3 — well inside the 5.7e-2 threshold.
__device__ inline float gelu_f(float x) {
  float x2 = x * x;
  float w  = x * fmaf(x2, 0.07135837f, 1.59576912f);
  float t  = w * -1.44269504f;
#if __has_builtin(__builtin_amdgcn_exp2f)
  float e  = __builtin_amdgcn_exp2f(t);
#else
  float e  = exp2f(t);
#endif
  return x * __builtin_amdgcn_rcpf(1.0f + e);
}

__global__ void zero_k(float* out) {
  if (threadIdx.x < 4) out[threadIdx.x] = 0.0f;
}

// Pack W[n][k] -> B-fragment layout: frag[tile][lane][j] = W[n][koff+k]
// with k = kt*32 + (lane>>4)*8 + j, n = nt*16 + (lane&15), tile = kt*NT + nt.
__global__ void pack_w(const float* __restrict__ W1, const float* __restrict__ W2,
                       const float* __restrict__ W3, unsigned short* __restrict__ pk) {
  int gid = blockIdx.x * 256 + threadIdx.x;   // 336 tiles * 64 lanes = 21504
  int tile = gid >> 6, lane = gid & 63;
  const float* W; int NT, ld, koff, lt; unsigned short* dst;
  if (tile < 128)      { W = W1; NT = 16; ld = 512; koff = 0;   lt = tile;       dst = pk + PK_W1A; }
  else if (tile < 256) { W = W1; NT = 16; ld = 512; koff = 256; lt = tile - 128; dst = pk + PK_W1Y; }
  else if (tile < 320) { W = W2; NT = 8;  ld = 256; koff = 0;   lt = tile - 256; dst = pk + PK_W2;  }
  else                 { W = W3; NT = 4;  ld = 128; koff = 0;   lt = tile - 320; dst = pk + PK_W3;  }
  int kt = lt / NT, nt = lt - kt * NT;
  int k = kt * 32 + (lane >> 4) * 8;
  int n = nt * 16 + (lane & 15);
  const float* src = W + (size_t)n * ld + koff + k;
  unsigned short o[8];
#pragma unroll
  for (int j = 0; j < 8; ++j) o[j] = f2b(src[j]);
  ushort4* d = (ushort4*)(dst + ((size_t)lt * 64 + lane) * 8);
  d[0] = make_ushort4(o[0], o[1], o[2], o[3]);
  d[1] = make_ushort4(o[4], o[5], o[6], o[7]);
}

// apre[m][n] = anchor[m] @ W1a^T + b1  (f32), M-tile = 64 rows / block
__global__ __launch_bounds__(256) void apre_k(const float* __restrict__ anchor,
                                              const float* __restrict__ b1,
                                              const unsigned short* __restrict__ pk,
                                              float* __restrict__ apre) {
  __shared__ __align__(16) unsigned short bufA[64 * 264];
  int t = threadIdx.x;
  int m0 = blockIdx.x * 64;
  for (int it = 0; it < 16; ++it) {
    int e = (it * 256 + t) * 4;
    int m = e >> 8, k = e & 255;
    float4 v = *(const float4*)(anchor + (size_t)(m0 + m) * 256 + k);
    *(uint2*)&bufA[m * 264 + k] = make_uint2(f2b2(v.x, v.y), f2b2(v.z, v.w));
  }
  __syncthreads();
  int wave = t >> 6, lane = t & 63, quad = lane >> 4, lid = lane & 15;
  f32x4 acc[4][4];
#pragma unroll
  for (int i = 0; i < 4; ++i)
#pragma unroll
    for (int j = 0; j < 4; ++j) { acc[i][j][0]=0.f; acc[i][j][1]=0.f; acc[i][j][2]=0.f; acc[i][j][3]=0.f; }
  const bf16x8* Wb = (const bf16x8*)(pk + PK_W1A);
  for (int kt = 0; kt < 8; ++kt) {
    bf16x8 a[4], b[4];
#pragma unroll
    for (int mt = 0; mt < 4; ++mt)
      a[mt] = *(const bf16x8*)&bufA[(mt * 16 + lid) * 264 + kt * 32 + quad * 8];
#pragma unroll
    for (int nt = 0; nt < 4; ++nt)
      b[nt] = Wb[(size_t)(kt * 16 + wave * 4 + nt) * 64 + lane];
#pragma unroll
    for (int mt = 0; mt < 4; ++mt)
#pragma unroll
      for (int nt = 0; nt < 4; ++nt)
        acc[mt][nt] = __builtin_amdgcn_mfma_f32_16x16x32_bf16(a[mt], b[nt], acc[mt][nt], 0, 0, 0);
  }
#pragma unroll
  for (int mt = 0; mt < 4; ++mt)
#pragma unroll
    for (int nt = 0; nt < 4; ++nt) {
      int n = wave * 64 + nt * 16 + lid;
      float bias = b1[n];
#pragma unroll
      for (int r = 0; r < 4; ++r) {
        int m = mt * 16 + quad * 4 + r;
        apre[(size_t)(m0 + m) * 256 + n] = acc[mt][nt][r] + bias;
      }
    }
}

// Fused per-pair MLP: 32 pairs per block, 4 waves (each owns an N-slice).
// LDS: bufA (y -> h1 -> h2 overlay) 16896 B + apre_s/epart 3072 B = 19968 B
// -> 8 blocks/CU by LDS; launch_bounds(256,6) targets 6 waves/SIMD by VGPR.
__global__ __launch_bounds__(256, 6) void fused_k(const float* __restrict__ positive,
                                                  const float* __restrict__ negatives,
                                                  const float* __restrict__ apre,
                                                  const unsigned short* __restrict__ pk,
                                                  const float* __restrict__ b2v,
                                                  const float* __restrict__ b3v,
                                                  const float* __restrict__ W4,
                                                  const float* __restrict__ b4v,
                                                  float* __restrict__ energies) {
  __shared__ __align__(16) unsigned short bufA[32 * 264];  // y, then h1, then h2 (stride 136)
  __shared__ __align__(16) float apre_s[3 * 256];          // apre rows; reused as epart[32][4]
  int t = threadIdx.x;
  int p0 = blockIdx.x * 32;
  int r0 = p0 / 17;
  int rN = (p0 + 31) / 17 - r0 + 1;   // <= 3
  for (int i = t; i < rN * 256; i += 256)
    apre_s[i] = apre[(size_t)(r0 + (i >> 8)) * 256 + (i & 255)];
#pragma unroll
  for (int it = 0; it < 8; ++it) {
    int e = (it * 256 + t) * 4;
    int m = e >> 8, k = e & 255;
    int p = p0 + m;
    int r = p / 17, c = p - r * 17;
    const float* src = (c == 0) ? (positive + (size_t)r * 256)
                                : (negatives + ((size_t)r * 16 + (c - 1)) * 256);
    float4 v = *(const float4*)(src + k);
    *(uint2*)&bufA[m * 264 + k] = make_uint2(f2b2(v.x, v.y), f2b2(v.z, v.w));
  }
  __syncthreads();
  int wave = t >> 6, lane = t & 63, quad = lane >> 4, lid = lane & 15;

  // ---- GEMM1: h1 = gelu(apre + y @ W1y^T); apre folded into MFMA C-in
  f32x4 acc[2][4];
  {
    int ri0[4], ri1[4];
#pragma unroll
    for (int r = 0; r < 4; ++r) ri0[r] = (p0 + quad * 4 + r) / 17 - r0;
#pragma unroll
    for (int r = 0; r < 4; ++r) ri1[r] = (p0 + 16 + quad * 4 + r) / 17 - r0;
#pragma unroll
    for (int nt = 0; nt < 4; ++nt) {
      int n = wave * 64 + nt * 16 + lid;
#pragma unroll
      for (int r = 0; r < 4; ++r) {
        acc[0][nt][r] = apre_s[ri0[r] * 256 + n];
        acc[1][nt][r] = apre_s[ri1[r] * 256 + n];
      }
    }
  }
  {
    const bf16x8* Wb = (const bf16x8*)(pk + PK_W1Y);
    for (int kt = 0; kt < 8; ++kt) {
      bf16x8 a[2], b[4];
#pragma unroll
      for (int mt = 0; mt < 2; ++mt)
        a[mt] = *(const bf16x8*)&bufA[(mt * 16 + lid) * 264 + kt * 32 + quad * 8];
#pragma unroll
      for (int nt = 0; nt < 4; ++nt)
        b[nt] = Wb[(size_t)(kt * 16 + wave * 4 + nt) * 64 + lane];
#pragma unroll
      for (int mt = 0; mt < 2; ++mt)
#pragma unroll
        for (int nt = 0; nt < 4; ++nt)
          acc[mt][nt] = __builtin_amdgcn_mfma_f32_16x16x32_bf16(a[mt], b[nt], acc[mt][nt], 0, 0, 0);
    }
  }
  __syncthreads();  // all waves done reading y before h1 overwrites bufA
#pragma unroll
  for (int mt = 0; mt < 2; ++mt)
#pragma unroll
    for (int nt = 0; nt < 4; ++nt) {
      int n = wave * 64 + nt * 16 + lid;
      int mb = mt * 16 + quad * 4;
      unsigned u01 = f2b2(gelu_f(acc[mt][nt][0]), gelu_f(acc[mt][nt][1]));
      unsigned u23 = f2b2(gelu_f(acc[mt][nt][2]), gelu_f(acc[mt][nt][3]));
      bufA[(mb + 0) * 264 + n] = (unsigned short)u01;
      bufA[(mb + 1) * 264 + n] = (unsigned short)(u01 >> 16);
      bufA[(mb + 2) * 264 + n] = (unsigned short)u23;
      bufA[(mb + 3) * 264 + n] = (unsigned short)(u23 >> 16);
    }
  __syncthreads();

  // ---- GEMM2: h2 = gelu(h1 @ W2^T + b2), N=128 (2 ntiles / wave); b2 as C-in
  f32x4 acc2[2][2];
  {
#pragma unroll
    for (int nt = 0; nt < 2; ++nt) {
      float bb = b2v[wave * 32 + nt * 16 + lid];
#pragma unroll
      for (int mt = 0; mt < 2; ++mt)
#pragma unroll
        for (int r = 0; r < 4; ++r) acc2[mt][nt][r] = bb;
    }
  }
  {
    const bf16x8* Wb = (const bf16x8*)(pk + PK_W2);
    for (int kt = 0; kt < 8; ++kt) {
      bf16x8 a[2], b[2];
#pragma unroll
      for (int mt = 0; mt < 2; ++mt)
        a[mt] = *(const bf16x8*)&bufA[(mt * 16 + lid) * 264 + kt * 32 + quad * 8];
#pragma unroll
      for (int nt = 0; nt < 2; ++nt)
        b[nt] = Wb[(size_t)(kt * 8 + wave * 2 + nt) * 64 + lane];
#pragma unroll
      for (int mt = 0; mt < 2; ++mt)
#pragma unroll
        for (int nt = 0; nt < 2; ++nt)
          acc2[mt][nt] = __builtin_amdgcn_mfma_f32_16x16x32_bf16(a[mt], b[nt], acc2[mt][nt], 0, 0, 0);
    }
  }
  __syncthreads();  // all waves done reading h1 before h2 overlays bufA
  unsigned short* bufC = bufA;   // h2 at stride 136 (4352 shorts used)
#pragma unroll
  for (int mt = 0; mt < 2; ++mt)
#pragma unroll
    for (int nt = 0; nt < 2; ++nt) {
      int n = wave * 32 + nt * 16 + lid;
      int mb = mt * 16 + quad * 4;
      unsigned u01 = f2b2(gelu_f(acc2[mt][nt][0]), gelu_f(acc2[mt][nt][1]));
      unsigned u23 = f2b2(gelu_f(acc2[mt][nt][2]), gelu_f(acc2[mt][nt][3]));
      bufC[(mb + 0) * 136 + n] = (unsigned short)u01;
      bufC[(mb + 1) * 136 + n] = (unsigned short)(u01 >> 16);
      bufC[(mb + 2) * 136 + n] = (unsigned short)u23;
      bufC[(mb + 3) * 136 + n] = (unsigned short)(u23 >> 16);
    }
  __syncthreads();

  // ---- GEMM3: h3 = gelu(h2 @ W3^T + b3), N=64 (1 ntile / wave); b3 as C-in.
  // h3 never touches LDS: layer-4 dot done in registers via shfl reduce.
  f32x4 acc3[2];
  {
    float bb = b3v[wave * 16 + lid];
#pragma unroll
    for (int mt = 0; mt < 2; ++mt)
#pragma unroll
      for (int r = 0; r < 4; ++r) acc3[mt][r] = bb;
  }
  {
    const bf16x8* Wb = (const bf16x8*)(pk + PK_W3);
    for (int kt = 0; kt < 4; ++kt) {
      bf16x8 a[2];
#pragma unroll
      for (int mt = 0; mt < 2; ++mt)
        a[mt] = *(const bf16x8*)&bufC[(mt * 16 + lid) * 136 + kt * 32 + quad * 8];
      bf16x8 b = Wb[(size_t)(kt * 4 + wave) * 64 + lane];
#pragma unroll
      for (int mt = 0; mt < 2; ++mt)
        acc3[mt] = __builtin_amdgcn_mfma_f32_16x16x32_bf16(a[mt], b, acc3[mt], 0, 0, 0);
    }
  }
  // ---- layer 4: energy[m] = sum_n gelu(h3[m][n]) * W4[n] + b4
  // thread owns col n = wave*16+lid for 8 rows; reduce over 16 lid-lanes
  // (shfl_xor 1/2/4/8 stays within the quad), then 4-wave gather via LDS.
  {
    float w4n = W4[wave * 16 + lid];
    float* epart = apre_s;   // [32][4] overlay; apre_s dead since GEMM1 C-init
#pragma unroll
    for (int mt = 0; mt < 2; ++mt)
#pragma unroll
      for (int r = 0; r < 4; ++r) {
        float v = gelu_f(acc3[mt][r]) * w4n;
        v += __shfl_xor(v, 1);
        v += __shfl_xor(v, 2);
        v += __shfl_xor(v, 4);
        v += __shfl_xor(v, 8);
        if (lid == 0) epart[(mt * 16 + quad * 4 + r) * 4 + wave] = v;
      }
  }
  __syncthreads();
  if (t < 32) {
    const float* epart = apre_s;
    energies[p0 + t] = b4v[0] + epart[t * 4 + 0] + epart[t * 4 + 1]
                     + epart[t * 4 + 2] + epart[t * 4 + 3];
  }
}

__global__ __launch_bounds__(256) void reduce_k(const float* __restrict__ E,
                                                float* __restrict__ out) {
  __shared__ float sd[256];
  int r = blockIdx.x * 256 + threadIdx.x;  // grid 128*256 == 32768 rows exactly
  const float* ep = E + (size_t)r * 17;
  float e[17];
#pragma unroll
  for (int i = 0; i < 17; ++i) e[i] = ep[i];
  float li[17];
#pragma unroll
  for (int i = 0; i < 17; ++i) li[i] = -e[i] * INV_T;
  float lmax = li[0];
#pragma unroll
  for (int i = 1; i < 17; ++i) lmax = fmaxf(lmax, li[i]);
  float se = 0.f;
#pragma unroll
  for (int i = 0; i < 17; ++i) se += expf(li[i] - lmax);
  float loss_t = (logf(se) + lmax) - li[0];
  float posv = e[0];
  float negv = 0.f;
#pragma unroll
  for (int i = 1; i < 17; ++i) negv += e[i];
  int mi = 0; float mv = e[0];
#pragma unroll
  for (int i = 1; i < 17; ++i) if (e[i] < mv) { mv = e[i]; mi = i; }
  float accv = (mi == 0) ? 1.f : 0.f;

  float vals[4] = { loss_t, posv, negv, accv };
  const float scales[4] = { 1.0f / NROWS, 1.0f / NROWS, 1.0f / (NROWS * 16.0f), 1.0f / NROWS };
#pragma unroll
  for (int j = 0; j < 4; ++j) {
    sd[threadIdx.x] = vals[j];
    __syncthreads();
    for (int s = 128; s > 0; s >>= 1) {
      if (threadIdx.x < s) sd[threadIdx.x] += sd[threadIdx.x + s];
      __syncthreads();
    }
    if (threadIdx.x == 0) atomicAdd(out + j, sd[0] * scales[j]);
    __syncthreads();
  }
}

extern "C" void kernel_launch(void* const* d_in, const int* in_sizes, int n_in,
                              void* d_out, int out_size, void* d_ws, size_t ws_size,
                              hipStream_t stream) {
  (void)in_sizes; (void)n_in; (void)out_size; (void)ws_size;
  const float* anchor    = (const float*)d_in[0];
  const float* positive  = (const float*)d_in[1];
  const float* negatives = (const float*)d_in[2];
  const float* W1 = (const float*)d_in[3];
  const float* b1 = (const float*)d_in[4];
  const float* W2 = (const float*)d_in[5];
  const float* b2 = (const float*)d_in[6];
  const float* W3 = (const float*)d_in[7];
  const float* b3 = (const float*)d_in[8];
  const float* W4 = (const float*)d_in[9];
  const float* b4 = (const float*)d_in[10];
  float* out = (float*)d_out;
  unsigned short* pk = (unsigned short*)d_ws;
  float* apre = (float*)((char*)d_ws + APRE_OFF_BYTES);
  float* energies = (float*)((char*)d_ws + EN_OFF_BYTES);

  hipLaunchKernelGGL(zero_k, dim3(1), dim3(64), 0, stream, out);
  hipLaunchKernelGGL(pack_w, dim3(84), dim3(256), 0, stream, W1, W2, W3, pk);
  hipLaunchKernelGGL(apre_k, dim3(512), dim3(256), 0, stream, anchor, b1, pk, apre);
  hipLaunchKernelGGL(fused_k, dim3(NPAIRS / 32), dim3(256), 0, stream,
                     positive, negatives, apre, pk, b2, b3, W4, b4, energies);
  hipLaunchKernelGGL(reduce_k, dim3(128), dim3(256), 0, stream, energies, out);
}